// Round 1
// baseline (81.843 us; speedup 1.0000x reference)
//
#include <hip/hip_runtime.h>
#include <cstdint>

// ATSS matcher, filter-then-select formulation (exact):
//  phaseZ: zero the 256 padded (gt,lvl) counters (16 KB)
//  scanK:  one block per 512 anchors, ALL 64 GTs per block (GT centers in LDS).
//          Reads raw anchors once (float2x3), computes centers in-register,
//          zeroes packed[] for its own range, gates d2<=T[level] -> atomic
//          append (packed d2,idx) to per-(gt,lvl) list. T = 3x expected 9th-NN
//          radius; pass rate ~244/GT/level. Correctness does NOT depend on T
//          (selectC has an exact full-rescan fallback); T only affects speed.
//  selectC: 256 threads = 4 waves per GT, one wave per FPN level: exact top-9
//          per (gt,lvl) from the tiny list (packed u64 compare == exact d2
//          order + lowest-index tie-break, matching jax top_k), fallback full
//          rescan if a list undercollected (<9) or overflowed; then wave 0
//          does fused IoU -> mean+std(ddof=1) threshold -> center-inside ->
//          atomicMax (iou<<32 | ~gt) argmax scatter.
//  phaseD: decode packed -> (matched_gt, matched_iou, labels) f32
//
// All arithmetic forms (center = (lo+hi)*0.5f, d2 = sa + sg - 2*dot) are kept
// byte-identical to the previously verified kernel so selection order matches.

#define NCAND 36
#define CAP 1024          // list capacity per (gt,lvl); expected fill ~244

__device__ __constant__ int   c_lvl_start[4] = {0, 262144, 294912, 299008};
__device__ __constant__ int   c_lvl_end[4]   = {262144, 294912, 299008, 299520};
// (3 * r9_bulk)^2 per level; r9_bulk = (9 / (4/3 pi rho))^(1/3), rho = lvl/512^3
__device__ __constant__ float c_T[4] = {961.0f, 3844.0f, 15376.0f, 61504.0f};

// order-preserving float->uint (handles negative d2 from cancellation)
__device__ inline unsigned f2ord(float f) {
    unsigned u = __float_as_uint(f);
    return (u & 0x80000000u) ? ~u : (u | 0x80000000u);
}

__device__ inline void insert9(unsigned long long* best, unsigned long long p) {
    if (p < best[8]) {
        int k = 8;
        while (k > 0 && best[k-1] > p) { best[k] = best[k-1]; k--; }
        best[k] = p;
    }
}

// merge two ascending sorted 9-lists, keep smallest 9 in a
__device__ inline void merge9(unsigned long long* a, const unsigned long long* b) {
    unsigned long long out[9];
    int ia = 0, ib = 0;
    #pragma unroll
    for (int k = 0; k < 9; k++) out[k] = (a[ia] <= b[ib]) ? a[ia++] : b[ib++];
    #pragma unroll
    for (int k = 0; k < 9; k++) a[k] = out[k];
}

__global__ void phaseZ(unsigned* __restrict__ cnt) {
    int i = blockIdx.x * blockDim.x + threadIdx.x;
    if (i < 256 * 16) cnt[i] = 0;
}

// one block per 512-anchor range (level bounds are all 512-multiples),
// 2 anchors/thread in regs, all m GTs from LDS. Also zeroes packed[] for its
// own range (each range owned by exactly one block).
__global__ void scanK(const float* __restrict__ anchors, const float* __restrict__ gt_boxes,
                      unsigned long long* __restrict__ lists, unsigned* __restrict__ cnt,
                      unsigned long long* __restrict__ packed, int n, int m) {
    int base = blockIdx.x << 9;
    int lvl  = (base >= 299008) ? 3 : (base >= 294912) ? 2 : (base >= 262144) ? 1 : 0;
    float T  = c_T[lvl];
    int tid  = threadIdx.x;

    __shared__ float4 gt4[64];
    if (tid < m) {
        int g = tid;
        float gx = (gt_boxes[g*6+0] + gt_boxes[g*6+2]) * 0.5f;
        float gy = (gt_boxes[g*6+1] + gt_boxes[g*6+3]) * 0.5f;
        float gz = (gt_boxes[g*6+4] + gt_boxes[g*6+5]) * 0.5f;
        float sg = gx*gx + gy*gy + gz*gz;
        gt4[g] = make_float4(gx, gy, gz, sg);
    }
    __syncthreads();

    float ax[2], ay[2], az[2], sa[2];
    int   ai[2]; bool av[2];
    #pragma unroll
    for (int k = 0; k < 2; k++) {
        int a = base + tid + k*256;
        ai[k] = a; av[k] = (a < n);
        if (av[k]) {
            const float2* r = (const float2*)(anchors + (size_t)a*6);
            float2 p0 = r[0], p1 = r[1], p2 = r[2];  // (x1,y1)(x2,y2)(z1,z2)
            float cx = (p0.x + p1.x) * 0.5f;
            float cy = (p0.y + p1.y) * 0.5f;
            float cz = (p2.x + p2.y) * 0.5f;
            ax[k] = cx; ay[k] = cy; az[k] = cz;
            sa[k] = cx*cx + cy*cy + cz*cz;
            packed[a] = 0ULL;
        } else {
            ax[k] = ay[k] = az[k] = sa[k] = 0.0f;
        }
    }

    for (int g = 0; g < m; g++) {
        float4 gv = gt4[g];
        int gidx = g*4 + lvl;
        #pragma unroll
        for (int k = 0; k < 2; k++) {
            float dot = ax[k]*gv.x + ay[k]*gv.y + az[k]*gv.z;
            float d2  = sa[k] + gv.w - 2.0f*dot;   // same algebraic form as reference
            if (av[k] && d2 <= T) {
                unsigned long long p =
                    ((unsigned long long)f2ord(d2) << 32) | (unsigned)ai[k];
                unsigned slot = atomicAdd(&cnt[gidx * 16], 1u);
                if (slot < CAP) lists[(size_t)gidx*CAP + slot] = p;
            }
        }
    }
}

// one block (256 threads = 4 waves) per GT; wave w handles FPN level w.
__global__ void selectC(const unsigned long long* __restrict__ lists,
                        const unsigned* __restrict__ cnt,
                        const float* __restrict__ anchors,
                        const float* __restrict__ gt_boxes,
                        unsigned long long* __restrict__ packed) {
    int g = blockIdx.x;
    int t = threadIdx.x;       // 0..255
    int lvl  = t >> 6;         // wave id == level
    int lane = t & 63;
    __shared__ int scand[NCAND];

    int gidx = g*4 + lvl;
    unsigned c = cnt[gidx * 16];   // issue early: head of the latency chain

    float gx1 = gt_boxes[g*6+0], gy1 = gt_boxes[g*6+1];
    float gx2 = gt_boxes[g*6+2], gy2 = gt_boxes[g*6+3];
    float gz1 = gt_boxes[g*6+4], gz2 = gt_boxes[g*6+5];
    float gx = (gx1+gx2)*0.5f, gy = (gy1+gy2)*0.5f, gz = (gz1+gz2)*0.5f;
    float sg = gx*gx + gy*gy + gz*gz;

    unsigned long long best[9];
    #pragma unroll
    for (int k = 0; k < 9; k++) best[k] = ~0ULL;

    if (c >= 9 && c <= CAP) {
        // normal path: exact top-9 of the filtered list
        for (unsigned s = lane; s < c; s += 64)
            insert9(best, lists[(size_t)gidx*CAP + s]);
    } else {
        // fallback: full exact rescan of this level (never expected)
        for (int i = c_lvl_start[lvl] + lane; i < c_lvl_end[lvl]; i += 64) {
            const float2* r = (const float2*)(anchors + (size_t)i*6);
            float2 p0 = r[0], p1 = r[1], p2 = r[2];
            float cx = (p0.x + p1.x) * 0.5f;
            float cy = (p0.y + p1.y) * 0.5f;
            float cz = (p2.x + p2.y) * 0.5f;
            float sa = cx*cx + cy*cy + cz*cz;
            float dot = cx*gx + cy*gy + cz*gz;
            float d2  = sa + sg - 2.0f*dot;
            insert9(best, ((unsigned long long)f2ord(d2) << 32) | (unsigned)i);
        }
    }
    // wave merge (lanes >= off produce don't-care values, never consumed)
    for (int off = 32; off >= 1; off >>= 1) {
        unsigned long long other[9];
        #pragma unroll
        for (int k = 0; k < 9; k++) other[k] = __shfl(best[k], lane + off);
        merge9(best, other);
    }
    if (lane == 0) {
        #pragma unroll
        for (int k = 0; k < 9; k++) scand[lvl*9 + k] = (int)(unsigned)best[k];
    }
    __syncthreads();

    if (t < 64) {
        float vg = (gx2 - gx1) * (gy2 - gy1) * (gz2 - gz1);
        bool valid = (t < NCAND);
        float iou = 0.0f;
        int aidx = 0;
        float acx = 0.0f, acy = 0.0f, acz = 0.0f;
        if (valid) {
            aidx = scand[t];
            float ax1 = anchors[aidx*6+0], ay1 = anchors[aidx*6+1];
            float ax2 = anchors[aidx*6+2], ay2 = anchors[aidx*6+3];
            float az1 = anchors[aidx*6+4], az2 = anchors[aidx*6+5];
            float va = (ax2 - ax1) * (ay2 - ay1) * (az2 - az1);
            float wx = fmaxf(fminf(ax2, gx2) - fmaxf(ax1, gx1), 0.0f);
            float wy = fmaxf(fminf(ay2, gy2) - fmaxf(ay1, gy1), 0.0f);
            float wz = fmaxf(fminf(az2, gz2) - fmaxf(az1, gz1), 0.0f);
            float inter = wx * wy * wz;
            iou = inter / (va + vg - inter + 1e-6f);
            acx = (ax1 + ax2) * 0.5f;
            acy = (ay1 + ay2) * 0.5f;
            acz = (az1 + az2) * 0.5f;
        }

        float s = iou;
        #pragma unroll
        for (int o = 32; o >= 1; o >>= 1) s += __shfl_xor(s, o);
        float mean = s / 36.0f;
        float dev = valid ? (iou - mean) : 0.0f;
        float s2 = dev * dev;
        #pragma unroll
        for (int o = 32; o >= 1; o >>= 1) s2 += __shfl_xor(s2, o);
        float thr = fmaxf(mean + sqrtf(s2 / 35.0f), 0.0f);  // MIN_IOU = 0

        if (valid && iou >= thr) {
            bool inside = (acx >= gx1) & (acx <= gx2) &
                          (acy >= gy1) & (acy <= gy2) &
                          (acz >= gz1) & (acz <= gz2);
            if (inside) {
                unsigned long long p =
                    ((unsigned long long)__float_as_uint(iou) << 32) | (unsigned)(~(unsigned)g);
                atomicMax(&packed[aidx], p);
            }
        }
    }
}

__global__ void phaseD(const unsigned long long* __restrict__ packed,
                       float* __restrict__ out, int n) {
    int i = blockIdx.x * blockDim.x + threadIdx.x;
    if (i >= n) return;
    unsigned long long p = packed[i];
    float gt_f, iou_f, lab_f;
    if (p == 0ULL) {
        gt_f = -1.0f; iou_f = 0.0f; lab_f = 0.0f;
    } else {
        unsigned low = (unsigned)p;
        int gidx = (int)(~low);
        iou_f = __uint_as_float((unsigned)(p >> 32));
        gt_f = (float)gidx;
        lab_f = 1.0f;
    }
    out[i]       = gt_f;
    out[n + i]   = iou_f;
    out[2*n + i] = lab_f;
}

extern "C" void kernel_launch(void* const* d_in, const int* in_sizes, int n_in,
                              void* d_out, int out_size, void* d_ws, size_t ws_size,
                              hipStream_t stream) {
    const float* gt      = (const float*)d_in[0];
    const float* anchors = (const float*)d_in[1];
    int m = in_sizes[0] / 6;   // 64
    int n = in_sizes[1] / 6;   // 299520

    char* ws = (char*)d_ws;
    unsigned long long* packed = (unsigned long long*)ws;                   // n*8
    unsigned long long* lists  = (unsigned long long*)(ws + (size_t)n * 8); // 256*CAP*8
    unsigned* cnt = (unsigned*)(ws + (size_t)n * 8 + (size_t)256*CAP*8);    // 256*64B

    float* out = (float*)d_out;

    int ablocks = (n + 511) / 512;   // 585; level bounds are 512-aligned
    phaseZ<<<16, 256, 0, stream>>>(cnt);
    scanK<<<ablocks, 256, 0, stream>>>(anchors, gt, lists, cnt, packed, n, m);
    selectC<<<m, 256, 0, stream>>>(lists, cnt, anchors, gt, packed);
    phaseD<<<(n + 255) / 256, 256, 0, stream>>>(packed, out, n);
}

// Round 2
// 78.000 us; speedup vs baseline: 1.0493x; 1.0493x over previous
//
#include <hip/hip_runtime.h>
#include <cstdint>

// ATSS matcher, filter-then-select formulation (exact):
//  phaseZ: zero the 256 padded (gt,lvl) counters + packed[] for levels 2/3
//  scanK:  levels 0/1 only (576 blocks x 512 anchors; level bound 262144 is
//          512-aligned). Reads raw anchors once (float2x3), centers in-register,
//          zeroes packed[] for its range, gates d2<=T[level]. Appends go to
//          per-GT LDS queues (ds_add_rtn ~100cy instead of a ~700cy global
//          atomic round trip serialized in the GT loop); one global atomicAdd
//          per (block,gt) at flush reserves a contiguous slot range. Queue
//          overflow (Poisson lambda<=7.6 vs cap 64: never) marks cnt+=2e6 ->
//          selectC exact full-rescan fallback. Correctness does NOT depend on
//          T or QCAP; they only affect speed.
//  selectC: 256 threads = 4 waves per GT, wave w = FPN level w. Waves 0/1:
//          exact top-9 from the filtered list (packed u64 compare == exact d2
//          order + lowest-index tie-break, matching jax top_k), fallback full
//          rescan if undercollected (<9) or overflowed. Waves 2/3: ALWAYS
//          direct full scan (4096 / 512 anchors -- cheaper than filtering).
//          Then wave 0 does fused IoU -> mean+std(ddof=1) threshold ->
//          center-inside -> atomicMax (iou<<32 | ~gt) argmax scatter.
//  phaseD: decode packed -> (matched_gt, matched_iou, labels) f32
//
// All arithmetic forms (center = (lo+hi)*0.5f, d2 = sa + sg - 2*dot) are kept
// byte-identical to the previously verified kernel so selection order matches.

#define NCAND 36
#define CAP 1024          // global list capacity per (gt,lvl); expected fill ~244
#define QCAP 64           // per-block per-gt LDS queue capacity
#define LVL2_START 294912

__device__ __constant__ int   c_lvl_start[4] = {0, 262144, 294912, 299008};
__device__ __constant__ int   c_lvl_end[4]   = {262144, 294912, 299008, 299520};
// (3 * r9_bulk)^2 per level; r9_bulk = (9 / (4/3 pi rho))^(1/3), rho = lvl/512^3
__device__ __constant__ float c_T[2] = {961.0f, 3844.0f};

// order-preserving float->uint (handles negative d2 from cancellation)
__device__ inline unsigned f2ord(float f) {
    unsigned u = __float_as_uint(f);
    return (u & 0x80000000u) ? ~u : (u | 0x80000000u);
}

__device__ inline void insert9(unsigned long long* best, unsigned long long p) {
    if (p < best[8]) {
        int k = 8;
        while (k > 0 && best[k-1] > p) { best[k] = best[k-1]; k--; }
        best[k] = p;
    }
}

// merge two ascending sorted 9-lists, keep smallest 9 in a
__device__ inline void merge9(unsigned long long* a, const unsigned long long* b) {
    unsigned long long out[9];
    int ia = 0, ib = 0;
    #pragma unroll
    for (int k = 0; k < 9; k++) out[k] = (a[ia] <= b[ib]) ? a[ia++] : b[ib++];
    #pragma unroll
    for (int k = 0; k < 9; k++) a[k] = out[k];
}

__global__ void phaseZ(unsigned* __restrict__ cnt, unsigned long long* __restrict__ packed,
                       int tail_start, int tail_len) {
    int i = blockIdx.x * blockDim.x + threadIdx.x;
    if (i < 256 * 16) cnt[i] = 0;
    int j = i - 256 * 16;
    if (j >= 0 && j < tail_len) packed[tail_start + j] = 0ULL;
}

// one block per 512-anchor range, levels 0/1 only. 2 anchors/thread in regs,
// all m GTs from LDS. Appends staged in per-GT LDS queues, flushed once.
__global__ void scanK(const float* __restrict__ anchors, const float* __restrict__ gt_boxes,
                      unsigned long long* __restrict__ lists, unsigned* __restrict__ cnt,
                      unsigned long long* __restrict__ packed, int n, int m) {
    int base = blockIdx.x << 9;
    int lvl  = (base >= 262144) ? 1 : 0;
    float T  = c_T[lvl];
    int tid  = threadIdx.x;

    __shared__ float4 gt4[64];
    __shared__ unsigned qcnt[64];
    __shared__ unsigned long long queue[64][QCAP];   // 32 KiB

    if (tid < 64) {
        qcnt[tid] = 0;
        if (tid < m) {
            int g = tid;
            float gx = (gt_boxes[g*6+0] + gt_boxes[g*6+2]) * 0.5f;
            float gy = (gt_boxes[g*6+1] + gt_boxes[g*6+3]) * 0.5f;
            float gz = (gt_boxes[g*6+4] + gt_boxes[g*6+5]) * 0.5f;
            float sg = gx*gx + gy*gy + gz*gz;
            gt4[g] = make_float4(gx, gy, gz, sg);
        }
    }
    __syncthreads();

    float ax[2], ay[2], az[2], sa[2];
    int   ai[2]; bool av[2];
    #pragma unroll
    for (int k = 0; k < 2; k++) {
        int a = base + tid + k*256;
        ai[k] = a; av[k] = (a < n);
        if (av[k]) {
            const float2* r = (const float2*)(anchors + (size_t)a*6);
            float2 p0 = r[0], p1 = r[1], p2 = r[2];  // (x1,y1)(x2,y2)(z1,z2)
            float cx = (p0.x + p1.x) * 0.5f;
            float cy = (p0.y + p1.y) * 0.5f;
            float cz = (p2.x + p2.y) * 0.5f;
            ax[k] = cx; ay[k] = cy; az[k] = cz;
            sa[k] = cx*cx + cy*cy + cz*cz;
            packed[a] = 0ULL;
        } else {
            ax[k] = ay[k] = az[k] = sa[k] = 0.0f;
        }
    }

    for (int g = 0; g < m; g++) {
        float4 gv = gt4[g];
        #pragma unroll
        for (int k = 0; k < 2; k++) {
            float dot = ax[k]*gv.x + ay[k]*gv.y + az[k]*gv.z;
            float d2  = sa[k] + gv.w - 2.0f*dot;   // same algebraic form as reference
            if (av[k] && d2 <= T) {
                unsigned long long p =
                    ((unsigned long long)f2ord(d2) << 32) | (unsigned)ai[k];
                unsigned idx = atomicAdd(&qcnt[g], 1u);   // LDS atomic
                if (idx < QCAP) queue[g][idx] = p;
            }
        }
    }
    __syncthreads();

    // flush: one global atomic per non-empty (block, gt)
    if (tid < 64) {
        int g = tid;
        unsigned c = qcnt[g];
        if (c > 0) {
            int gidx = g*4 + lvl;
            if (c > QCAP) {
                atomicAdd(&cnt[gidx * 16], 2000000u);  // force fallback rescan
            } else {
                unsigned bs = atomicAdd(&cnt[gidx * 16], c);
                for (unsigned j = 0; j < c; j++) {
                    unsigned s = bs + j;
                    if (s < CAP) lists[(size_t)gidx*CAP + s] = queue[g][j];
                }
            }
        }
    }
}

// one block (256 threads = 4 waves) per GT; wave w handles FPN level w.
__global__ void selectC(const unsigned long long* __restrict__ lists,
                        const unsigned* __restrict__ cnt,
                        const float* __restrict__ anchors,
                        const float* __restrict__ gt_boxes,
                        unsigned long long* __restrict__ packed, int n) {
    int g = blockIdx.x;
    int t = threadIdx.x;       // 0..255
    int lvl  = t >> 6;         // wave id == level
    int lane = t & 63;
    __shared__ int scand[NCAND];

    unsigned c = 0;
    if (lvl < 2) c = cnt[(g*4 + lvl) * 16];   // issue early

    float gx1 = gt_boxes[g*6+0], gy1 = gt_boxes[g*6+1];
    float gx2 = gt_boxes[g*6+2], gy2 = gt_boxes[g*6+3];
    float gz1 = gt_boxes[g*6+4], gz2 = gt_boxes[g*6+5];
    float gx = (gx1+gx2)*0.5f, gy = (gy1+gy2)*0.5f, gz = (gz1+gz2)*0.5f;
    float sg = gx*gx + gy*gy + gz*gz;

    unsigned long long best[9];
    #pragma unroll
    for (int k = 0; k < 9; k++) best[k] = ~0ULL;

    if (lvl < 2 && c >= 9 && c <= CAP) {
        // normal path: exact top-9 of the filtered list
        size_t off = (size_t)(g*4 + lvl) * CAP;
        for (unsigned s = lane; s < c; s += 64)
            insert9(best, lists[off + s]);
    } else {
        // exact full scan of this level (always for lvl 2/3; fallback for 0/1)
        int s0 = c_lvl_start[lvl], s1 = c_lvl_end[lvl];
        if (s1 > n) s1 = n;
        int i = s0 + lane;
        // 4-wide batching: 12 independent loads in flight per iteration
        for (; i + 192 < s1; i += 256) {
            float2 q[4][3];
            #pragma unroll
            for (int u = 0; u < 4; u++) {
                const float2* r = (const float2*)(anchors + (size_t)(i + u*64)*6);
                q[u][0] = r[0]; q[u][1] = r[1]; q[u][2] = r[2];
            }
            #pragma unroll
            for (int u = 0; u < 4; u++) {
                float cx = (q[u][0].x + q[u][1].x) * 0.5f;
                float cy = (q[u][0].y + q[u][1].y) * 0.5f;
                float cz = (q[u][2].x + q[u][2].y) * 0.5f;
                float sa = cx*cx + cy*cy + cz*cz;
                float dot = cx*gx + cy*gy + cz*gz;
                float d2  = sa + sg - 2.0f*dot;
                insert9(best, ((unsigned long long)f2ord(d2) << 32) | (unsigned)(i + u*64));
            }
        }
        for (; i < s1; i += 64) {
            const float2* r = (const float2*)(anchors + (size_t)i*6);
            float2 p0 = r[0], p1 = r[1], p2 = r[2];
            float cx = (p0.x + p1.x) * 0.5f;
            float cy = (p0.y + p1.y) * 0.5f;
            float cz = (p2.x + p2.y) * 0.5f;
            float sa = cx*cx + cy*cy + cz*cz;
            float dot = cx*gx + cy*gy + cz*gz;
            float d2  = sa + sg - 2.0f*dot;
            insert9(best, ((unsigned long long)f2ord(d2) << 32) | (unsigned)i);
        }
    }
    // wave merge (lanes >= off produce don't-care values, never consumed)
    for (int off = 32; off >= 1; off >>= 1) {
        unsigned long long other[9];
        #pragma unroll
        for (int k = 0; k < 9; k++) other[k] = __shfl(best[k], lane + off);
        merge9(best, other);
    }
    if (lane == 0) {
        #pragma unroll
        for (int k = 0; k < 9; k++) scand[lvl*9 + k] = (int)(unsigned)best[k];
    }
    __syncthreads();

    if (t < 64) {
        float vg = (gx2 - gx1) * (gy2 - gy1) * (gz2 - gz1);
        bool valid = (t < NCAND);
        float iou = 0.0f;
        int aidx = 0;
        float acx = 0.0f, acy = 0.0f, acz = 0.0f;
        if (valid) {
            aidx = scand[t];
            float ax1 = anchors[aidx*6+0], ay1 = anchors[aidx*6+1];
            float ax2 = anchors[aidx*6+2], ay2 = anchors[aidx*6+3];
            float az1 = anchors[aidx*6+4], az2 = anchors[aidx*6+5];
            float va = (ax2 - ax1) * (ay2 - ay1) * (az2 - az1);
            float wx = fmaxf(fminf(ax2, gx2) - fmaxf(ax1, gx1), 0.0f);
            float wy = fmaxf(fminf(ay2, gy2) - fmaxf(ay1, gy1), 0.0f);
            float wz = fmaxf(fminf(az2, gz2) - fmaxf(az1, gz1), 0.0f);
            float inter = wx * wy * wz;
            iou = inter / (va + vg - inter + 1e-6f);
            acx = (ax1 + ax2) * 0.5f;
            acy = (ay1 + ay2) * 0.5f;
            acz = (az1 + az2) * 0.5f;
        }

        float s = iou;
        #pragma unroll
        for (int o = 32; o >= 1; o >>= 1) s += __shfl_xor(s, o);
        float mean = s / 36.0f;
        float dev = valid ? (iou - mean) : 0.0f;
        float s2 = dev * dev;
        #pragma unroll
        for (int o = 32; o >= 1; o >>= 1) s2 += __shfl_xor(s2, o);
        float thr = fmaxf(mean + sqrtf(s2 / 35.0f), 0.0f);  // MIN_IOU = 0

        if (valid && iou >= thr) {
            bool inside = (acx >= gx1) & (acx <= gx2) &
                          (acy >= gy1) & (acy <= gy2) &
                          (acz >= gz1) & (acz <= gz2);
            if (inside) {
                unsigned long long p =
                    ((unsigned long long)__float_as_uint(iou) << 32) | (unsigned)(~(unsigned)g);
                atomicMax(&packed[aidx], p);
            }
        }
    }
}

__global__ void phaseD(const unsigned long long* __restrict__ packed,
                       float* __restrict__ out, int n) {
    int i = blockIdx.x * blockDim.x + threadIdx.x;
    if (i >= n) return;
    unsigned long long p = packed[i];
    float gt_f, iou_f, lab_f;
    if (p == 0ULL) {
        gt_f = -1.0f; iou_f = 0.0f; lab_f = 0.0f;
    } else {
        unsigned low = (unsigned)p;
        int gidx = (int)(~low);
        iou_f = __uint_as_float((unsigned)(p >> 32));
        gt_f = (float)gidx;
        lab_f = 1.0f;
    }
    out[i]       = gt_f;
    out[n + i]   = iou_f;
    out[2*n + i] = lab_f;
}

extern "C" void kernel_launch(void* const* d_in, const int* in_sizes, int n_in,
                              void* d_out, int out_size, void* d_ws, size_t ws_size,
                              hipStream_t stream) {
    const float* gt      = (const float*)d_in[0];
    const float* anchors = (const float*)d_in[1];
    int m = in_sizes[0] / 6;   // 64
    int n = in_sizes[1] / 6;   // 299520

    char* ws = (char*)d_ws;
    unsigned long long* packed = (unsigned long long*)ws;                   // n*8
    unsigned long long* lists  = (unsigned long long*)(ws + (size_t)n * 8); // 256*CAP*8
    unsigned* cnt = (unsigned*)(ws + (size_t)n * 8 + (size_t)256*CAP*8);    // 256*64B

    float* out = (float*)d_out;

    int tail_len = n - LVL2_START;                       // 4608
    int zitems = 256*16 + tail_len;
    phaseZ<<<(zitems + 255) / 256, 256, 0, stream>>>(cnt, packed, LVL2_START, tail_len);
    scanK<<<LVL2_START / 512, 256, 0, stream>>>(anchors, gt, lists, cnt, packed, n, m);
    selectC<<<m, 256, 0, stream>>>(lists, cnt, anchors, gt, packed, n);
    phaseD<<<(n + 255) / 256, 256, 0, stream>>>(packed, out, n);
}

// Round 3
// 46.222 us; speedup vs baseline: 1.7707x; 1.6875x over previous
//
#include <hip/hip_runtime.h>
#include <cstdint>

// ATSS matcher, filter-then-select formulation (exact):
//  phaseZ: zero the 256 padded (gt,lvl) counters + packed[] for level 3
//  scanK:  levels 0/1/2 (584 blocks x 512 anchors; all level bounds are
//          512-aligned). Reads raw anchors once (float2x3), centers in
//          registers, zeroes packed[] for its range, gates d2<=T[level].
//          Appends go to per-GT LDS queues (LDS atomic instead of a ~700cy
//          global atomic round trip serialized in the GT loop); one global
//          atomicAdd per (block,gt) at flush reserves a contiguous range.
//          Queue overflow marks cnt+=2e6 -> selectC exact fallback, so
//          correctness does NOT depend on T or QCAP; they only affect speed.
//  selectC: 256 threads = 4 waves per GT, wave w = FPN level w. ALL selection
//          state is in named registers with static indexing (NO runtime-
//          indexed local arrays -> no scratch). Waves 0-2: up to 8 list
//          elements per lane (c<=512; else branch-free full-rescan fallback,
//          never expected). Wave 3: direct-computes its 512 anchors (8/lane).
//          Top-9 = 9 rounds of wave-wide argmin-with-removal on packed u64
//          (== exact d2 order + lowest-index tie-break, matching jax top_k).
//          Then wave 0 does fused IoU -> mean+std(ddof=1) threshold ->
//          center-inside -> atomicMax (iou<<32 | ~gt) argmax scatter.
//  phaseD: decode packed -> (matched_gt, matched_iou, labels) f32
//
// All arithmetic forms (center = (lo+hi)*0.5f, d2 = sa + sg - 2*dot) are kept
// byte-identical to the previously verified kernel so selection order matches.

#define NCAND 36
#define CAP 1024          // global list capacity per (gt,lvl); expected fill ~244
#define LISTMAX 512       // max usable list length in selectC (8 per lane)
#define QCAP 64           // per-block per-gt LDS queue capacity
#define LVL3_START 299008

__device__ __constant__ int   c_lvl_start[4] = {0, 262144, 294912, 299008};
__device__ __constant__ int   c_lvl_end[4]   = {262144, 294912, 299008, 299520};
// (3 * r9_bulk)^2 per level; r9_bulk = (9 / (4/3 pi rho))^(1/3), rho = lvl/512^3
__device__ __constant__ float c_T[3] = {961.0f, 3844.0f, 15376.0f};

// order-preserving float->uint (handles negative d2 from cancellation)
__device__ inline unsigned f2ord(float f) {
    unsigned u = __float_as_uint(f);
    return (u & 0x80000000u) ? ~u : (u | 0x80000000u);
}

__global__ void phaseZ(unsigned* __restrict__ cnt, unsigned long long* __restrict__ packed,
                       int tail_start, int tail_len) {
    int i = blockIdx.x * blockDim.x + threadIdx.x;
    if (i < 256 * 16) cnt[i] = 0;
    int j = i - 256 * 16;
    if (j >= 0 && j < tail_len) packed[tail_start + j] = 0ULL;
}

// one block per 512-anchor range, levels 0/1/2. 2 anchors/thread in regs,
// all m GTs from LDS. Appends staged in per-GT LDS queues, flushed once.
__global__ void scanK(const float* __restrict__ anchors, const float* __restrict__ gt_boxes,
                      unsigned long long* __restrict__ lists, unsigned* __restrict__ cnt,
                      unsigned long long* __restrict__ packed, int n, int m) {
    int base = blockIdx.x << 9;
    int lvl  = (base >= 294912) ? 2 : (base >= 262144) ? 1 : 0;
    float T  = c_T[lvl];
    int tid  = threadIdx.x;

    __shared__ float4 gt4[64];
    __shared__ unsigned qcnt[64];
    __shared__ unsigned long long queue[64][QCAP];   // 32 KiB

    if (tid < 64) {
        qcnt[tid] = 0;
        if (tid < m) {
            int g = tid;
            float gx = (gt_boxes[g*6+0] + gt_boxes[g*6+2]) * 0.5f;
            float gy = (gt_boxes[g*6+1] + gt_boxes[g*6+3]) * 0.5f;
            float gz = (gt_boxes[g*6+4] + gt_boxes[g*6+5]) * 0.5f;
            float sg = gx*gx + gy*gy + gz*gz;
            gt4[g] = make_float4(gx, gy, gz, sg);
        }
    }
    __syncthreads();

    float ax[2], ay[2], az[2], sa[2];
    int   ai[2]; bool av[2];
    #pragma unroll
    for (int k = 0; k < 2; k++) {
        int a = base + tid + k*256;
        ai[k] = a; av[k] = (a < n);
        if (av[k]) {
            const float2* r = (const float2*)(anchors + (size_t)a*6);
            float2 p0 = r[0], p1 = r[1], p2 = r[2];  // (x1,y1)(x2,y2)(z1,z2)
            float cx = (p0.x + p1.x) * 0.5f;
            float cy = (p0.y + p1.y) * 0.5f;
            float cz = (p2.x + p2.y) * 0.5f;
            ax[k] = cx; ay[k] = cy; az[k] = cz;
            sa[k] = cx*cx + cy*cy + cz*cz;
            packed[a] = 0ULL;
        } else {
            ax[k] = ay[k] = az[k] = sa[k] = 0.0f;
        }
    }

    for (int g = 0; g < m; g++) {
        float4 gv = gt4[g];
        #pragma unroll
        for (int k = 0; k < 2; k++) {
            float dot = ax[k]*gv.x + ay[k]*gv.y + az[k]*gv.z;
            float d2  = sa[k] + gv.w - 2.0f*dot;   // same algebraic form as reference
            if (av[k] && d2 <= T) {
                unsigned long long p =
                    ((unsigned long long)f2ord(d2) << 32) | (unsigned)ai[k];
                unsigned idx = atomicAdd(&qcnt[g], 1u);   // LDS atomic
                if (idx < QCAP) queue[g][idx] = p;
            }
        }
    }
    __syncthreads();

    // flush: one global atomic per non-empty (block, gt)
    if (tid < 64) {
        int g = tid;
        unsigned c = qcnt[g];
        if (c > 0) {
            int gidx = g*4 + lvl;
            if (c > QCAP) {
                atomicAdd(&cnt[gidx * 16], 2000000u);  // force fallback rescan
            } else {
                unsigned bs = atomicAdd(&cnt[gidx * 16], c);
                for (unsigned j = 0; j < c; j++) {
                    unsigned s = bs + j;
                    if (s < CAP) lists[(size_t)gidx*CAP + s] = queue[g][j];
                }
            }
        }
    }
}

// one block (256 threads = 4 waves) per GT; wave w handles FPN level w.
// All candidate state in named registers (static indexing only).
__global__ void selectC(const unsigned long long* __restrict__ lists,
                        const unsigned* __restrict__ cnt,
                        const float* __restrict__ anchors,
                        const float* __restrict__ gt_boxes,
                        unsigned long long* __restrict__ packed, int n) {
    int g = blockIdx.x;
    int t = threadIdx.x;       // 0..255
    int lvl  = t >> 6;         // wave id == level
    int lane = t & 63;
    __shared__ int scand[NCAND];

    unsigned c = 0;
    if (lvl < 3) c = cnt[(g*4 + lvl) * 16];   // issue early

    float gx1 = gt_boxes[g*6+0], gy1 = gt_boxes[g*6+1];
    float gx2 = gt_boxes[g*6+2], gy2 = gt_boxes[g*6+3];
    float gz1 = gt_boxes[g*6+4], gz2 = gt_boxes[g*6+5];
    float gx = (gx1+gx2)*0.5f, gy = (gy1+gy2)*0.5f, gz = (gz1+gz2)*0.5f;
    float sg = gx*gx + gy*gy + gz*gz;

    unsigned long long e[9];
    #pragma unroll
    for (int k = 0; k < 9; k++) e[k] = ~0ULL;

    if (lvl == 3) {
        // direct: exactly 512 anchors = 8 per lane, all in registers
        #pragma unroll
        for (int j = 0; j < 8; j++) {
            int i = LVL3_START + lane + 64*j;
            if (i < n) {
                const float2* r = (const float2*)(anchors + (size_t)i*6);
                float2 p0 = r[0], p1 = r[1], p2 = r[2];
                float cx = (p0.x + p1.x) * 0.5f;
                float cy = (p0.y + p1.y) * 0.5f;
                float cz = (p2.x + p2.y) * 0.5f;
                float sa = cx*cx + cy*cy + cz*cz;
                float dot = cx*gx + cy*gy + cz*gz;
                float d2  = sa + sg - 2.0f*dot;
                e[j] = ((unsigned long long)f2ord(d2) << 32) | (unsigned)i;
            }
        }
    } else if (c >= 9 && c <= LISTMAX) {
        // normal path: whole filtered list into registers (<=8 per lane)
        size_t off = (size_t)(g*4 + lvl) * CAP;
        #pragma unroll
        for (int j = 0; j < 8; j++) {
            unsigned s = (unsigned)lane + 64u*j;
            if (s < c) e[j] = lists[off + s];
        }
    } else {
        // fallback: full exact rescan, branch-free register top-9 (never expected)
        int s0 = c_lvl_start[lvl], s1 = c_lvl_end[lvl];
        if (s1 > n) s1 = n;
        for (int i = s0 + lane; i < s1; i += 64) {
            const float2* r = (const float2*)(anchors + (size_t)i*6);
            float2 p0 = r[0], p1 = r[1], p2 = r[2];
            float cx = (p0.x + p1.x) * 0.5f;
            float cy = (p0.y + p1.y) * 0.5f;
            float cz = (p2.x + p2.y) * 0.5f;
            float sa = cx*cx + cy*cy + cz*cz;
            float dot = cx*gx + cy*gy + cz*gz;
            float d2  = sa + sg - 2.0f*dot;
            unsigned long long x = ((unsigned long long)f2ord(d2) << 32) | (unsigned)i;
            if (x < e[8]) {
                #pragma unroll
                for (int k = 0; k < 9; k++) {     // static-index min/max chain
                    unsigned long long lo = (x < e[k]) ? x : e[k];
                    unsigned long long hi = (x < e[k]) ? e[k] : x;
                    e[k] = lo; x = hi;
                }
            }
        }
    }

    // exact top-9: 9 rounds of wave-wide argmin with removal.
    // packed keys are unique (anchor idx in low bits), so each round removes
    // exactly one element globally; >=9 real elements exist on every path.
    #pragma unroll
    for (int r9 = 0; r9 < 9; r9++) {
        unsigned long long mn = e[0];
        #pragma unroll
        for (int j = 1; j < 9; j++) mn = (e[j] < mn) ? e[j] : mn;
        #pragma unroll
        for (int off = 32; off >= 1; off >>= 1) {
            unsigned long long o = __shfl_xor(mn, off);
            mn = (o < mn) ? o : mn;
        }
        if (lane == 0) scand[lvl*9 + r9] = (int)(unsigned)mn;
        #pragma unroll
        for (int j = 0; j < 9; j++) e[j] = (e[j] == mn) ? ~0ULL : e[j];
    }
    __syncthreads();

    if (t < 64) {
        float vg = (gx2 - gx1) * (gy2 - gy1) * (gz2 - gz1);
        bool valid = (t < NCAND);
        float iou = 0.0f;
        int aidx = 0;
        float acx = 0.0f, acy = 0.0f, acz = 0.0f;
        if (valid) {
            aidx = scand[t];
            float ax1 = anchors[aidx*6+0], ay1 = anchors[aidx*6+1];
            float ax2 = anchors[aidx*6+2], ay2 = anchors[aidx*6+3];
            float az1 = anchors[aidx*6+4], az2 = anchors[aidx*6+5];
            float va = (ax2 - ax1) * (ay2 - ay1) * (az2 - az1);
            float wx = fmaxf(fminf(ax2, gx2) - fmaxf(ax1, gx1), 0.0f);
            float wy = fmaxf(fminf(ay2, gy2) - fmaxf(ay1, gy1), 0.0f);
            float wz = fmaxf(fminf(az2, gz2) - fmaxf(az1, gz1), 0.0f);
            float inter = wx * wy * wz;
            iou = inter / (va + vg - inter + 1e-6f);
            acx = (ax1 + ax2) * 0.5f;
            acy = (ay1 + ay2) * 0.5f;
            acz = (az1 + az2) * 0.5f;
        }

        float s = iou;
        #pragma unroll
        for (int o = 32; o >= 1; o >>= 1) s += __shfl_xor(s, o);
        float mean = s / 36.0f;
        float dev = valid ? (iou - mean) : 0.0f;
        float s2 = dev * dev;
        #pragma unroll
        for (int o = 32; o >= 1; o >>= 1) s2 += __shfl_xor(s2, o);
        float thr = fmaxf(mean + sqrtf(s2 / 35.0f), 0.0f);  // MIN_IOU = 0

        if (valid && iou >= thr) {
            bool inside = (acx >= gx1) & (acx <= gx2) &
                          (acy >= gy1) & (acy <= gy2) &
                          (acz >= gz1) & (acz <= gz2);
            if (inside) {
                unsigned long long p =
                    ((unsigned long long)__float_as_uint(iou) << 32) | (unsigned)(~(unsigned)g);
                atomicMax(&packed[aidx], p);
            }
        }
    }
}

__global__ void phaseD(const unsigned long long* __restrict__ packed,
                       float* __restrict__ out, int n) {
    int i = blockIdx.x * blockDim.x + threadIdx.x;
    if (i >= n) return;
    unsigned long long p = packed[i];
    float gt_f, iou_f, lab_f;
    if (p == 0ULL) {
        gt_f = -1.0f; iou_f = 0.0f; lab_f = 0.0f;
    } else {
        unsigned low = (unsigned)p;
        int gidx = (int)(~low);
        iou_f = __uint_as_float((unsigned)(p >> 32));
        gt_f = (float)gidx;
        lab_f = 1.0f;
    }
    out[i]       = gt_f;
    out[n + i]   = iou_f;
    out[2*n + i] = lab_f;
}

extern "C" void kernel_launch(void* const* d_in, const int* in_sizes, int n_in,
                              void* d_out, int out_size, void* d_ws, size_t ws_size,
                              hipStream_t stream) {
    const float* gt      = (const float*)d_in[0];
    const float* anchors = (const float*)d_in[1];
    int m = in_sizes[0] / 6;   // 64
    int n = in_sizes[1] / 6;   // 299520

    char* ws = (char*)d_ws;
    unsigned long long* packed = (unsigned long long*)ws;                   // n*8
    unsigned long long* lists  = (unsigned long long*)(ws + (size_t)n * 8); // 256*CAP*8
    unsigned* cnt = (unsigned*)(ws + (size_t)n * 8 + (size_t)256*CAP*8);    // 256*64B

    float* out = (float*)d_out;

    int tail_len = n - LVL3_START;                       // 512
    int zitems = 256*16 + tail_len;
    phaseZ<<<(zitems + 255) / 256, 256, 0, stream>>>(cnt, packed, LVL3_START, tail_len);
    scanK<<<LVL3_START / 512, 256, 0, stream>>>(anchors, gt, lists, cnt, packed, n, m);
    selectC<<<m, 256, 0, stream>>>(lists, cnt, anchors, gt, packed, n);
    phaseD<<<(n + 255) / 256, 256, 0, stream>>>(packed, out, n);
}